// Round 18
// baseline (635.799 us; speedup 1.0000x reference)
//
#include <hip/hip_runtime.h>

#define NN 50000
#define NE 800000
#define DD 64
#define NL 5
#define NG 256
#define NC 10
#define BN_EPS 1e-5f
#define NCHUNK ((NN + 255) / 256)   // 196
#define GROWS 128                    // rows per gemm block
#define GT (GROWS / 16)              // 16-row tiles per block
#define SAW 68                       // staged-A row stride (uints)
#define GEMM_BLOCKS ((NN + GROWS - 1) / GROWS)   // 391

typedef __attribute__((ext_vector_type(8))) short bf16x8;
typedef __attribute__((ext_vector_type(4))) float f32x4;

__device__ inline float bf2f(unsigned short u) {
    return __uint_as_float((unsigned)u << 16);
}
__device__ inline unsigned short f2bf(float x) {   // RNE
    unsigned u = __float_as_uint(x);
    u += 0x7FFFu + ((u >> 16) & 1u);
    return (unsigned short)(u >> 16);
}

// Pack two floats as bf16 (RNE) into one uint: low16 = a, high16 = b.
__device__ inline unsigned int pack_bf16x2(float a, float b) {
    unsigned int ua = __float_as_uint(a);
    unsigned int ub = __float_as_uint(b);
    ua += 0x7FFFu + ((ua >> 16) & 1u);
    ub += 0x7FFFu + ((ub >> 16) & 1u);
    return (ub & 0xFFFF0000u) | (ua >> 16);
}

// Split fp32 into bf16 hi (RTZ) + bf16 lo (residual). hi+lo ~ x to ~2^-17.
__device__ inline void split_bf16(float x, short& h, short& l) {
    const unsigned u  = __float_as_uint(x);
    const unsigned hb = u & 0xFFFF0000u;
    h = (short)(hb >> 16);
    const float lo = x - __uint_as_float(hb);
    l = (short)(__float_as_uint(lo) >> 16);
}

// gate-fma with PRE-EXPONENTIATED gate inputs: p packs (e^-q | v) bf16.
// sigmoid(k+q) = 1/(1 + e^-k * e^-q). One rcp per gate.
__device__ inline float gate_fma(float ek, unsigned p, float acc) {
    const float eq = __uint_as_float(p << 16);
    const float v  = __uint_as_float(p & 0xFFFF0000u);
    const float t  = fmaf(ek, eq, 1.f);
    return fmaf(__builtin_amdgcn_rcpf(t), v, acc);
}

// ---------------------------------------------------------------------------
// W-fragment prep (all 5 layers upfront): split W into MFMA-read-order
// bf16 hi/lo fragment buffers. t = l*2048 + m*512 + c*256 + w*64 + lane.
// ---------------------------------------------------------------------------
__global__ __launch_bounds__(256) void wprep_kernel(
    const float* __restrict__ Wk, const float* __restrict__ Wq,
    const float* __restrict__ Wv, const float* __restrict__ Ws,
    bf16x8* __restrict__ whbuf, bf16x8* __restrict__ wlbuf)
{
    const int t = blockIdx.x * 256 + threadIdx.x;
    if (t >= NL * 2048) return;
    const int lane = t & 63;
    const int w    = (t >> 6) & 3;
    const int c    = (t >> 8) & 1;
    const int m    = (t >> 9) & 3;
    const int l    = t >> 11;

    const float* Wm4[4] = {Wk, Wq, Wv, Ws};
    const float* W = Wm4[m] + l * 4096;
    const int col = w * 16 + (lane & 15);
    const int g   = lane >> 4;

    bf16x8 h, lo;
#pragma unroll
    for (int j = 0; j < 8; j++) {
        const int k = g * 8 + j + 32 * c;
        short hs, ls;
        split_bf16(W[k * DD + col], hs, ls);
        h[j] = hs; lo[j] = ls;
    }
    whbuf[t] = h;
    wlbuf[t] = lo;
}

// ---------------------------------------------------------------------------
// MFMA gemm4 (inline prev-layer BN, QUARTER-MAJOR outputs):
//   Kq/QVq/Hq[quarter][node][16]. QVq packs (e^-q | v) — exp done here,
// once per (node,col), amortized over deg~16 edge-uses in gather.
// ---------------------------------------------------------------------------
__global__ __launch_bounds__(256) void gemm4_mfma(
    const void* __restrict__ HinV, const int hinF32,
    const bf16x8* __restrict__ whbuf, const bf16x8* __restrict__ wlbuf,
    const float* __restrict__ bk, const float* __restrict__ bq,
    const float* __restrict__ bv, const float* __restrict__ bs,
    const float* __restrict__ prevStats,   // null for layer 0
    const float* __restrict__ prevGamma, const float* __restrict__ prevBeta,
    unsigned short* __restrict__ Kq, unsigned int* __restrict__ QVq,
    unsigned short* __restrict__ Hq)
{
    __shared__ unsigned int sA[GROWS * SAW];   // packed split-bf16 A
    __shared__ float sAB[128];                 // a[64], b[64]
    const int tid = threadIdx.x;

    if (tid < 64) {
        float a = 1.f, b = 0.f;
        if (prevStats) {
            const float invN = 1.0f / (float)NN;
            const float mean = prevStats[tid] * invN;
            const float var  = prevStats[64 + tid] * invN - mean * mean;
            const float inv  = rsqrtf(var + BN_EPS);
            a = inv * prevGamma[tid];
            b = prevBeta[tid] - mean * a;
        }
        sAB[tid]      = a;
        sAB[64 + tid] = b;
    }
    __syncthreads();

    const int row0 = blockIdx.x * GROWS;
    if (hinF32) {
        const float* X = (const float*)HinV;
        for (int i = tid; i < GROWS * 16; i += 256) {
            const int row = i >> 4;
            const int k4  = (i & 15) * 4;
            float4 x = make_float4(0.f, 0.f, 0.f, 0.f);
            if (row0 + row < NN)
                x = *(const float4*)(X + (size_t)(row0 + row) * DD + k4);
            const float xs[4] = {x.x, x.y, x.z, x.w};
            unsigned int* dst = &sA[row * SAW + k4];
#pragma unroll
            for (int j = 0; j < 4; j++) {
                const float xv = fmaf(xs[j], sAB[k4 + j], sAB[64 + k4 + j]);
                short hs, ls;
                split_bf16(xv, hs, ls);
                dst[j] = ((unsigned int)(unsigned short)hs << 16) | (unsigned short)ls;
            }
        }
    } else {
        const unsigned short* Hin = (const unsigned short*)HinV;
        for (int i = tid; i < GROWS * 8; i += 256) {
            const int row = i >> 3;
            const int cb  = (i & 7) * 8;   // col base: 0,8,..,56
            const int q   = cb >> 4;
            const int o16 = cb & 15;       // 0 or 8
            uint4 v = make_uint4(0u, 0u, 0u, 0u);
            if (row0 + row < NN)
                v = *(const uint4*)&Hin[((size_t)q * NN + row0 + row) * 16 + o16];
            const unsigned ws[4] = {v.x, v.y, v.z, v.w};
            unsigned int* dst = &sA[row * SAW + cb];
#pragma unroll
            for (int j = 0; j < 4; j++) {
                const float x0 = bf2f((unsigned short)(ws[j] & 0xFFFFu));
                const float x1 = bf2f((unsigned short)(ws[j] >> 16));
                const int c0 = cb + 2 * j, c1 = cb + 2 * j + 1;
                short hs, ls;
                split_bf16(fmaf(x0, sAB[c0], sAB[64 + c0]), hs, ls);
                dst[2 * j] = ((unsigned int)(unsigned short)hs << 16) | (unsigned short)ls;
                split_bf16(fmaf(x1, sAB[c1], sAB[64 + c1]), hs, ls);
                dst[2 * j + 1] = ((unsigned int)(unsigned short)hs << 16) | (unsigned short)ls;
            }
        }
    }

    const int wave = tid >> 6;    // column tile == quarter
    const int lane = tid & 63;
    const int n15  = lane & 15;
    const int g    = lane >> 4;
    const int col  = wave * 16 + n15;

    bf16x8 wh[4][2], wl[4][2];
    {
        const int base = wave * 64 + lane;
#pragma unroll
        for (int m = 0; m < 4; m++)
#pragma unroll
            for (int c = 0; c < 2; c++) {
                const int idx = m * 512 + c * 256 + base;
                wh[m][c] = whbuf[idx];
                wl[m][c] = wlbuf[idx];
            }
    }

    const float bkc = bk[col], bqc = bq[col], bvc = bv[col], bsc = bs[col];
    __syncthreads();

#pragma unroll 1
    for (int t = 0; t < GT; t++) {
        const int rowbase = row0 + t * 16;
        if (rowbase >= NN) break;   // NN % 16 == 0

        bf16x8 ah[2], al[2];
#pragma unroll
        for (int c = 0; c < 2; c++) {
            const uint4 u0 = *(const uint4*)&sA[(t * 16 + n15) * SAW + g * 8 + 32 * c];
            const uint4 u1 = *(const uint4*)&sA[(t * 16 + n15) * SAW + g * 8 + 32 * c + 4];
            const unsigned int us[8] = {u0.x, u0.y, u0.z, u0.w, u1.x, u1.y, u1.z, u1.w};
            bf16x8 h, l;
#pragma unroll
            for (int j = 0; j < 8; j++) {
                h[j] = (short)(us[j] >> 16);
                l[j] = (short)(us[j] & 0xFFFFu);
            }
            ah[c] = h; al[c] = l;
        }

        f32x4 acc[4];
#pragma unroll
        for (int m = 0; m < 4; m++) acc[m] = (f32x4){0.f, 0.f, 0.f, 0.f};

#pragma unroll
        for (int c = 0; c < 2; c++) {
#pragma unroll
            for (int m = 0; m < 4; m++) {
                acc[m] = __builtin_amdgcn_mfma_f32_16x16x32_bf16(ah[c], wh[m][c], acc[m], 0, 0, 0);
                acc[m] = __builtin_amdgcn_mfma_f32_16x16x32_bf16(al[c], wh[m][c], acc[m], 0, 0, 0);
                acc[m] = __builtin_amdgcn_mfma_f32_16x16x32_bf16(ah[c], wl[m][c], acc[m], 0, 0, 0);
            }
        }

#pragma unroll
        for (int r = 0; r < 4; r++) {
            const int row = rowbase + g * 4 + r;
            const size_t o = ((size_t)wave * NN + row) * 16 + n15;
            Kq[o]  = f2bf(acc[0][r] + bkc);
            QVq[o] = pack_bf16x2(__expf(-(acc[1][r] + bqc)), acc[2][r] + bvc);
            Hq[o]  = f2bf(acc[3][r] + bsc);
        }
    }
}

// ---------------------------------------------------------------------------
// CSR build: histogram of dst, two-level exclusive scan, scatter fill (u16).
// ---------------------------------------------------------------------------
__global__ __launch_bounds__(256) void deg_kernel(
    const int* __restrict__ ei, int* __restrict__ deg)
{
    const int e = blockIdx.x * 256 + threadIdx.x;
    if (e < NE) atomicAdd(&deg[ei[NE + e]], 1);
}

__global__ __launch_bounds__(256) void scan_partial_kernel(
    const int* __restrict__ deg, int* __restrict__ psums)
{
    __shared__ int ls[256];
    const int i = blockIdx.x * 256 + threadIdx.x;
    ls[threadIdx.x] = (i < NN) ? deg[i] : 0;
    __syncthreads();
    for (int off = 128; off > 0; off >>= 1) {
        if (threadIdx.x < off) ls[threadIdx.x] += ls[threadIdx.x + off];
        __syncthreads();
    }
    if (threadIdx.x == 0) psums[blockIdx.x] = ls[0];
}

__global__ void scan_offsets_kernel(int* __restrict__ psums, int* __restrict__ rowst)
{
    if (threadIdx.x == 0) {
        int running = 0;
        for (int i = 0; i < NCHUNK; i++) {
            int t = psums[i];
            psums[i] = running;
            running += t;
        }
        rowst[NN] = running;  // == NE
    }
}

__global__ __launch_bounds__(256) void scan_final_kernel(
    const int* __restrict__ deg, const int* __restrict__ psums,
    int* __restrict__ rowst, int* __restrict__ cursor)
{
    __shared__ int ls[256];
    const int i = blockIdx.x * 256 + threadIdx.x;
    const int x = (i < NN) ? deg[i] : 0;
    ls[threadIdx.x] = x;
    __syncthreads();
    for (int off = 1; off < 256; off <<= 1) {
        int v = (threadIdx.x >= off) ? ls[threadIdx.x - off] : 0;
        __syncthreads();
        ls[threadIdx.x] += v;
        __syncthreads();
    }
    if (i < NN) {
        const int excl = psums[blockIdx.x] + ls[threadIdx.x] - x;
        rowst[i]  = excl;
        cursor[i] = excl;
    }
}

__global__ __launch_bounds__(256) void fill_kernel(
    const int* __restrict__ ei, int* __restrict__ cursor,
    unsigned short* __restrict__ csr16)
{
    const int e = blockIdx.x * 256 + threadIdx.x;
    if (e < NE) {
        const int src = ei[e];         // < 50000 < 65536 -> u16 exact
        const int dst = ei[NE + e];
        csr16[atomicAdd(&cursor[dst], 1)] = (unsigned short)src;
    }
}

// ---------------------------------------------------------------------------
// Column-quarter XCD-partitioned gather with STREAMING PREFETCH prologue:
// block j first streams its 4 KB chunk of the quarter's QVq slice (one
// uint4/thread, asm sink) -> the resident cohort fills each XCD's L2 at
// streaming BW instead of scattered 64B cold misses at latency. Then the
// R16 dual-node unroll-8 gather (4 independent Qq loads in flight).
// Per node: ONE exp (e^-k); per edge: one rcp.
// ---------------------------------------------------------------------------
#define GATHER_BLOCKS (8 * 782)   // 6256
__global__ __launch_bounds__(256) void gather_kernel(
    const int* __restrict__ rowst, const unsigned short* __restrict__ csr16,
    const unsigned short* __restrict__ Kq, const unsigned int* __restrict__ QVq,
    unsigned short* Hq, float* __restrict__ stats)
{
    const int tid  = threadIdx.x;
    const int wv   = tid >> 6;
    const int lane = tid & 63;
    const int eoff = lane >> 4;     // edge slot 0..3
    const int cl   = lane & 15;     // column within quarter

    const int j       = blockIdx.x;
    const int xcd     = j & 7;
    const int quarter = xcd >> 1;
    const int half    = xcd & 1;
    const int nodebase = ((j >> 3) * 2 + half) * 32 + wv * 8;

    const unsigned short* Kqq = Kq + (size_t)quarter * NN * 16;
    const unsigned int*   Qq  = QVq + (size_t)quarter * NN * 16;
    unsigned short*       Hqq = Hq + (size_t)quarter * NN * 16;

    // ---- streaming prefetch: 782 chunks x 1024 uints cover NN*16=800000 ----
    {
        const int base = (j >> 3) * 1024 + tid * 4;
        if (base + 3 < NN * 16) {
            const uint4 p = *(const uint4*)&Qq[base];
            asm volatile("" :: "v"(p.x), "v"(p.y), "v"(p.z), "v"(p.w));
        }
    }

    float s = 0.f, s2 = 0.f;

    for (int t = 0; t < 4; t++) {
        const int n0 = nodebase + 2 * t;     // even; n1 = n0+1 < NN when n0 < NN
        if (n0 >= NN) break;
        const int n1 = n0 + 1;
        const float ek0 = __expf(-bf2f(Kqq[(unsigned)(n0 * 16 + cl)]));
        const float ek1 = __expf(-bf2f(Kqq[(unsigned)(n1 * 16 + cl)]));
        const int e00 = rowst[n0], e01 = rowst[n1], e11 = rowst[n1 + 1];
        float a0 = 0.f, a1 = 0.f;
        int i0 = e00, i1 = e01;

        // main: 4 independent Qq loads in flight (2 per node)
        while (i0 + 8 <= e01 && i1 + 8 <= e11) {
            const int s00 = csr16[i0 + eoff];
            const int s01 = csr16[i0 + 4 + eoff];
            const int s10 = csr16[i1 + eoff];
            const int s11 = csr16[i1 + 4 + eoff];
            const unsigned p00 = Qq[(unsigned)(s00 * 16 + cl)];
            const unsigned p01 = Qq[(unsigned)(s01 * 16 + cl)];
            const unsigned p10 = Qq[(unsigned)(s10 * 16 + cl)];
            const unsigned p11 = Qq[(unsigned)(s11 * 16 + cl)];
            a0 = gate_fma(ek0, p00, a0);
            a0 = gate_fma(ek0, p01, a0);
            a1 = gate_fma(ek1, p10, a1);
            a1 = gate_fma(ek1, p11, a1);
            i0 += 8; i1 += 8;
        }
        // node-0 cleanup
        for (; i0 + 4 <= e01; i0 += 4) {
            const int s0 = csr16[i0 + eoff];
            a0 = gate_fma(ek0, Qq[(unsigned)(s0 * 16 + cl)], a0);
        }
        if (i0 < e01) {
            const int idx = min(i0 + eoff, e01 - 1);
            const float gv = gate_fma(ek0, Qq[(unsigned)(csr16[idx] * 16 + cl)], 0.f);
            a0 += (i0 + eoff < e01) ? gv : 0.f;
        }
        // node-1 cleanup
        for (; i1 + 4 <= e11; i1 += 4) {
            const int s1 = csr16[i1 + eoff];
            a1 = gate_fma(ek1, Qq[(unsigned)(s1 * 16 + cl)], a1);
        }
        if (i1 < e11) {
            const int idx = min(i1 + eoff, e11 - 1);
            const float gv = gate_fma(ek1, Qq[(unsigned)(csr16[idx] * 16 + cl)], 0.f);
            a1 += (i1 + eoff < e11) ? gv : 0.f;
        }

        // combine edge slots (lanes l, l+16, l+32, l+48 share a column)
        a0 += __shfl_xor(a0, 16);
        a0 += __shfl_xor(a0, 32);
        a1 += __shfl_xor(a1, 16);
        a1 += __shfl_xor(a1, 32);
        if (eoff == 0) {
            const unsigned ho0 = (unsigned)(n0 * 16 + cl);
            const unsigned ho1 = (unsigned)(n1 * 16 + cl);
            const float o0 = fmaxf(bf2f(Hqq[ho0]) + a0, 0.f);
            const float o1 = fmaxf(bf2f(Hqq[ho1]) + a1, 0.f);
            const unsigned short ob0 = f2bf(o0);
            const unsigned short ob1 = f2bf(o1);
            Hqq[ho0] = ob0;
            Hqq[ho1] = ob1;
            const float r0 = bf2f(ob0), r1 = bf2f(ob1);
            s += r0 + r1;
            s2 += r0 * r0 + r1 * r1;
        }
    }

    __shared__ float ls[64], ls2[64];   // 4 waves x 16 cols
    if (eoff == 0) {
        ls[wv * 16 + cl]  = s;
        ls2[wv * 16 + cl] = s2;
    }
    __syncthreads();
    if (tid < 16) {
        const float a = ls[tid] + ls[16 + tid] + ls[32 + tid] + ls[48 + tid];
        const float b = ls2[tid] + ls2[16 + tid] + ls2[32 + tid] + ls2[48 + tid];
        atomicAdd(&stats[quarter * 16 + tid], a);
        atomicAdd(&stats[64 + quarter * 16 + tid], b);
    }
}

// ---------------------------------------------------------------------------
// Pooled segment-sum over quarter-major bf16 H (batch sorted).
// ---------------------------------------------------------------------------
#define POOL_ROWS 64
__global__ __launch_bounds__(64) void pool_kernel(
    const unsigned short* __restrict__ Hq, const int* __restrict__ batch,
    float* __restrict__ psum, float* __restrict__ pcnt)
{
    const int c  = threadIdx.x;
    const int q  = c >> 4;
    const int cl = c & 15;
    const int r0 = blockIdx.x * POOL_ROWS;
    if (r0 >= NN) return;
    const int r1 = min(r0 + POOL_ROWS, NN);
    const unsigned short* Hqq = Hq + (size_t)q * NN * 16;

    int cur = batch[r0];
    float acc = 0.f, cnt = 0.f;
    for (int r = r0; r < r1; r++) {
        const int g = batch[r];
        if (g != cur) {
            atomicAdd(&psum[cur * DD + c], acc);
            if (c == 0) atomicAdd(&pcnt[cur], cnt);
            acc = 0.f; cnt = 0.f; cur = g;
        }
        acc += bf2f(Hqq[(size_t)r * 16 + cl]);
        cnt += 1.f;
    }
    atomicAdd(&psum[cur * DD + c], acc);
    if (c == 0) atomicAdd(&pcnt[cur], cnt);
}

// ---------------------------------------------------------------------------
// Final: pooled mean -> folded last-layer BN affine -> logits -> softmax.
// ---------------------------------------------------------------------------
__global__ __launch_bounds__(256) void final_kernel(
    const float* __restrict__ psum, const float* __restrict__ pcnt,
    const float* __restrict__ stats,
    const float* __restrict__ gamma, const float* __restrict__ beta,
    const float* __restrict__ Wlin, const float* __restrict__ blin,
    float* __restrict__ out)
{
    const int g = blockIdx.x * blockDim.x + threadIdx.x;
    if (g >= NG) return;

    const float invc = 1.0f / fmaxf(pcnt[g], 1.0f);
    const float invN = 1.0f / (float)NN;
    float p[DD];
#pragma unroll
    for (int d = 0; d < DD; d++) {
        const float mean = stats[d] * invN;
        const float var  = stats[64 + d] * invN - mean * mean;
        const float inv  = rsqrtf(var + BN_EPS);
        const float a = inv * gamma[d];
        const float b = beta[d] - mean * a;
        p[d] = fmaf(psum[g * DD + d] * invc, a, b);
    }

    float logits[NC];
    float m = -1e30f;
#pragma unroll
    for (int c = 0; c < NC; c++) {
        float acc = blin[c];
#pragma unroll
        for (int d = 0; d < DD; d++) acc = fmaf(p[d], Wlin[d * NC + c], acc);
        logits[c] = acc;
        m = fmaxf(m, acc);
    }
    float sum = 0.f;
#pragma unroll
    for (int c = 0; c < NC; c++) {
        logits[c] = __expf(logits[c] - m);
        sum += logits[c];
    }
    const float inv = 1.f / sum;
#pragma unroll
    for (int c = 0; c < NC; c++) out[g * NC + c] = logits[c] * inv;
}

// ---------------------------------------------------------------------------
extern "C" void kernel_launch(void* const* d_in, const int* in_sizes, int n_in,
                              void* d_out, int out_size, void* d_ws, size_t ws_size,
                              hipStream_t stream)
{
    const float* X     = (const float*)d_in[0];
    const int*   ei    = (const int*)d_in[1];
    const int*   batch = (const int*)d_in[2];
    const float* Wk    = (const float*)d_in[3];
    const float* Wq    = (const float*)d_in[4];
    const float* Wv    = (const float*)d_in[5];
    const float* Ws    = (const float*)d_in[6];
    const float* bk    = (const float*)d_in[7];
    const float* bq    = (const float*)d_in[8];
    const float* bv    = (const float*)d_in[9];
    const float* bconv = (const float*)d_in[10];
    const float* gamma = (const float*)d_in[11];
    const float* beta  = (const float*)d_in[12];
    const float* Wlin  = (const float*)d_in[13];
    const float* blin  = (const float*)d_in[14];
    float* out = (float*)d_out;

    const size_t M = (size_t)NN * DD;   // == 4 * NN * 16
    unsigned short* Kq  = (unsigned short*)d_ws;      // M bf16, quarter-major
    unsigned int*   QVq = (unsigned int*)(Kq + M);    // M packed (e^-q|v)
    unsigned short* H0q = (unsigned short*)(QVq + M); // M bf16, quarter-major
    unsigned short* H1q = H0q + M;                    // M bf16
    // --- contiguous zero-init region ---
    int*   deg   = (int*)(H1q + M);                   // NN
    float* psum  = (float*)(deg + NN);                // NG*DD
    float* pcnt  = psum + (size_t)NG * DD;            // NG
    float* stats = pcnt + NG;                         // NL*128
    // --- end zero region ---
    int* rowst  = (int*)(stats + NL * 128);           // NN+1
    int* cursor = rowst + NN + 1;                     // NN
    int* psums  = cursor + NN;                        // 256
    unsigned short* csr16 = (unsigned short*)(psums + 256);  // NE u16
    bf16x8* whbuf = (bf16x8*)(csr16 + NE);            // NL*2048 frags
    bf16x8* wlbuf = whbuf + NL * 2048;

    const size_t zero_bytes = (size_t)(NN + NG * DD + NG + NL * 128) * sizeof(float);
    hipMemsetAsync(deg, 0, zero_bytes, stream);

    // ---- W fragment prep (all layers) ----
    wprep_kernel<<<(NL * 2048 + 255) / 256, 256, 0, stream>>>(
        Wk, Wq, Wv, Ws, whbuf, wlbuf);

    // ---- CSR build (u16 adjacency) ----
    deg_kernel<<<(NE + 255) / 256, 256, 0, stream>>>(ei, deg);
    scan_partial_kernel<<<NCHUNK, 256, 0, stream>>>(deg, psums);
    scan_offsets_kernel<<<1, 64, 0, stream>>>(psums, rowst);
    scan_final_kernel<<<NCHUNK, 256, 0, stream>>>(deg, psums, rowst, cursor);
    fill_kernel<<<(NE + 255) / 256, 256, 0, stream>>>(ei, cursor, csr16);

    // ---- layers (BN folded into next GEMM / final) ----
    const void* hin = (const void*)X;
    int hinF32 = 1;
    for (int l = 0; l < NL; l++) {
        unsigned short* hout = (l & 1) ? H1q : H0q;
        const float* pS = l ? stats + (l - 1) * 128 : nullptr;
        const float* pG = l ? gamma + (l - 1) * 64  : nullptr;
        const float* pB = l ? beta  + (l - 1) * 64  : nullptr;
        gemm4_mfma<<<GEMM_BLOCKS, 256, 0, stream>>>(
            hin, hinF32, whbuf + l * 2048, wlbuf + l * 2048,
            bk + l * 64, bq + l * 64, bv + l * 64, bconv + l * 64,
            pS, pG, pB, Kq, QVq, hout);
        gather_kernel<<<GATHER_BLOCKS, 256, 0, stream>>>(
            rowst, csr16, Kq, QVq, hout, stats + l * 128);
        hin = (const void*)hout;
        hinF32 = 0;
    }

    pool_kernel<<<(NN + POOL_ROWS - 1) / POOL_ROWS, 64, 0, stream>>>(
        (const unsigned short*)hin, batch, psum, pcnt);
    final_kernel<<<1, 256, 0, stream>>>(
        psum, pcnt, stats + 4 * 128, gamma + 4 * 64, beta + 4 * 64, Wlin, blin, out);
}

// Round 19
// 630.424 us; speedup vs baseline: 1.0085x; 1.0085x over previous
//
#include <hip/hip_runtime.h>

#define NN 50000
#define NE 800000
#define DD 64
#define NL 5
#define NG 256
#define NC 10
#define BN_EPS 1e-5f
#define NCHUNK ((NN + 255) / 256)   // 196
#define GROWS 128                    // rows per gemm block
#define GT (GROWS / 16)              // 16-row tiles per block
#define SAW 68                       // staged-A row stride (uints)
#define GEMM_BLOCKS ((NN + GROWS - 1) / GROWS)   // 391

typedef __attribute__((ext_vector_type(8))) short bf16x8;
typedef __attribute__((ext_vector_type(4))) float f32x4;

__device__ inline float bf2f(unsigned short u) {
    return __uint_as_float((unsigned)u << 16);
}
__device__ inline unsigned short f2bf(float x) {   // RNE
    unsigned u = __float_as_uint(x);
    u += 0x7FFFu + ((u >> 16) & 1u);
    return (unsigned short)(u >> 16);
}

// Pack two floats as bf16 (RNE) into one uint: low16 = a, high16 = b.
__device__ inline unsigned int pack_bf16x2(float a, float b) {
    unsigned int ua = __float_as_uint(a);
    unsigned int ub = __float_as_uint(b);
    ua += 0x7FFFu + ((ua >> 16) & 1u);
    ub += 0x7FFFu + ((ub >> 16) & 1u);
    return (ub & 0xFFFF0000u) | (ua >> 16);
}

// Split fp32 into bf16 hi (RTZ) + bf16 lo (residual). hi+lo ~ x to ~2^-17.
__device__ inline void split_bf16(float x, short& h, short& l) {
    const unsigned u  = __float_as_uint(x);
    const unsigned hb = u & 0xFFFF0000u;
    h = (short)(hb >> 16);
    const float lo = x - __uint_as_float(hb);
    l = (short)(__float_as_uint(lo) >> 16);
}

// gate-fma with PRE-EXPONENTIATED gate inputs: p packs (e^-q | v) bf16.
// sigmoid(k+q) = 1/(1 + e^-k * e^-q). One rcp per gate.
__device__ inline float gate_fma(float ek, unsigned p, float acc) {
    const float eq = __uint_as_float(p << 16);
    const float v  = __uint_as_float(p & 0xFFFF0000u);
    const float t  = fmaf(ek, eq, 1.f);
    return fmaf(__builtin_amdgcn_rcpf(t), v, acc);
}

// ---------------------------------------------------------------------------
// W-fragment prep (all 5 layers upfront): split W into MFMA-read-order
// bf16 hi/lo fragment buffers. t = l*2048 + m*512 + c*256 + w*64 + lane.
// ---------------------------------------------------------------------------
__global__ __launch_bounds__(256) void wprep_kernel(
    const float* __restrict__ Wk, const float* __restrict__ Wq,
    const float* __restrict__ Wv, const float* __restrict__ Ws,
    bf16x8* __restrict__ whbuf, bf16x8* __restrict__ wlbuf)
{
    const int t = blockIdx.x * 256 + threadIdx.x;
    if (t >= NL * 2048) return;
    const int lane = t & 63;
    const int w    = (t >> 6) & 3;
    const int c    = (t >> 8) & 1;
    const int m    = (t >> 9) & 3;
    const int l    = t >> 11;

    const float* Wm4[4] = {Wk, Wq, Wv, Ws};
    const float* W = Wm4[m] + l * 4096;
    const int col = w * 16 + (lane & 15);
    const int g   = lane >> 4;

    bf16x8 h, lo;
#pragma unroll
    for (int j = 0; j < 8; j++) {
        const int k = g * 8 + j + 32 * c;
        short hs, ls;
        split_bf16(W[k * DD + col], hs, ls);
        h[j] = hs; lo[j] = ls;
    }
    whbuf[t] = h;
    wlbuf[t] = lo;
}

// ---------------------------------------------------------------------------
// MFMA gemm4 (inline prev-layer BN, QUARTER-MAJOR outputs):
//   Kq/QVq/Hq[quarter][node][16]. QVq packs (e^-q | v) — exp done here,
// once per (node,col), amortized over deg~16 edge-uses in gather.
// ---------------------------------------------------------------------------
__global__ __launch_bounds__(256) void gemm4_mfma(
    const void* __restrict__ HinV, const int hinF32,
    const bf16x8* __restrict__ whbuf, const bf16x8* __restrict__ wlbuf,
    const float* __restrict__ bk, const float* __restrict__ bq,
    const float* __restrict__ bv, const float* __restrict__ bs,
    const float* __restrict__ prevStats,   // null for layer 0
    const float* __restrict__ prevGamma, const float* __restrict__ prevBeta,
    unsigned short* __restrict__ Kq, unsigned int* __restrict__ QVq,
    unsigned short* __restrict__ Hq)
{
    __shared__ unsigned int sA[GROWS * SAW];   // packed split-bf16 A
    __shared__ float sAB[128];                 // a[64], b[64]
    const int tid = threadIdx.x;

    if (tid < 64) {
        float a = 1.f, b = 0.f;
        if (prevStats) {
            const float invN = 1.0f / (float)NN;
            const float mean = prevStats[tid] * invN;
            const float var  = prevStats[64 + tid] * invN - mean * mean;
            const float inv  = rsqrtf(var + BN_EPS);
            a = inv * prevGamma[tid];
            b = prevBeta[tid] - mean * a;
        }
        sAB[tid]      = a;
        sAB[64 + tid] = b;
    }
    __syncthreads();

    const int row0 = blockIdx.x * GROWS;
    if (hinF32) {
        const float* X = (const float*)HinV;
        for (int i = tid; i < GROWS * 16; i += 256) {
            const int row = i >> 4;
            const int k4  = (i & 15) * 4;
            float4 x = make_float4(0.f, 0.f, 0.f, 0.f);
            if (row0 + row < NN)
                x = *(const float4*)(X + (size_t)(row0 + row) * DD + k4);
            const float xs[4] = {x.x, x.y, x.z, x.w};
            unsigned int* dst = &sA[row * SAW + k4];
#pragma unroll
            for (int j = 0; j < 4; j++) {
                const float xv = fmaf(xs[j], sAB[k4 + j], sAB[64 + k4 + j]);
                short hs, ls;
                split_bf16(xv, hs, ls);
                dst[j] = ((unsigned int)(unsigned short)hs << 16) | (unsigned short)ls;
            }
        }
    } else {
        const unsigned short* Hin = (const unsigned short*)HinV;
        for (int i = tid; i < GROWS * 8; i += 256) {
            const int row = i >> 3;
            const int cb  = (i & 7) * 8;   // col base: 0,8,..,56
            const int q   = cb >> 4;
            const int o16 = cb & 15;       // 0 or 8
            uint4 v = make_uint4(0u, 0u, 0u, 0u);
            if (row0 + row < NN)
                v = *(const uint4*)&Hin[((size_t)q * NN + row0 + row) * 16 + o16];
            const unsigned ws[4] = {v.x, v.y, v.z, v.w};
            unsigned int* dst = &sA[row * SAW + cb];
#pragma unroll
            for (int j = 0; j < 4; j++) {
                const float x0 = bf2f((unsigned short)(ws[j] & 0xFFFFu));
                const float x1 = bf2f((unsigned short)(ws[j] >> 16));
                const int c0 = cb + 2 * j, c1 = cb + 2 * j + 1;
                short hs, ls;
                split_bf16(fmaf(x0, sAB[c0], sAB[64 + c0]), hs, ls);
                dst[2 * j] = ((unsigned int)(unsigned short)hs << 16) | (unsigned short)ls;
                split_bf16(fmaf(x1, sAB[c1], sAB[64 + c1]), hs, ls);
                dst[2 * j + 1] = ((unsigned int)(unsigned short)hs << 16) | (unsigned short)ls;
            }
        }
    }

    const int wave = tid >> 6;    // column tile == quarter
    const int lane = tid & 63;
    const int n15  = lane & 15;
    const int g    = lane >> 4;
    const int col  = wave * 16 + n15;

    bf16x8 wh[4][2], wl[4][2];
    {
        const int base = wave * 64 + lane;
#pragma unroll
        for (int m = 0; m < 4; m++)
#pragma unroll
            for (int c = 0; c < 2; c++) {
                const int idx = m * 512 + c * 256 + base;
                wh[m][c] = whbuf[idx];
                wl[m][c] = wlbuf[idx];
            }
    }

    const float bkc = bk[col], bqc = bq[col], bvc = bv[col], bsc = bs[col];
    __syncthreads();

#pragma unroll 1
    for (int t = 0; t < GT; t++) {
        const int rowbase = row0 + t * 16;
        if (rowbase >= NN) break;   // NN % 16 == 0

        bf16x8 ah[2], al[2];
#pragma unroll
        for (int c = 0; c < 2; c++) {
            const uint4 u0 = *(const uint4*)&sA[(t * 16 + n15) * SAW + g * 8 + 32 * c];
            const uint4 u1 = *(const uint4*)&sA[(t * 16 + n15) * SAW + g * 8 + 32 * c + 4];
            const unsigned int us[8] = {u0.x, u0.y, u0.z, u0.w, u1.x, u1.y, u1.z, u1.w};
            bf16x8 h, l;
#pragma unroll
            for (int j = 0; j < 8; j++) {
                h[j] = (short)(us[j] >> 16);
                l[j] = (short)(us[j] & 0xFFFFu);
            }
            ah[c] = h; al[c] = l;
        }

        f32x4 acc[4];
#pragma unroll
        for (int m = 0; m < 4; m++) acc[m] = (f32x4){0.f, 0.f, 0.f, 0.f};

#pragma unroll
        for (int c = 0; c < 2; c++) {
#pragma unroll
            for (int m = 0; m < 4; m++) {
                acc[m] = __builtin_amdgcn_mfma_f32_16x16x32_bf16(ah[c], wh[m][c], acc[m], 0, 0, 0);
                acc[m] = __builtin_amdgcn_mfma_f32_16x16x32_bf16(al[c], wh[m][c], acc[m], 0, 0, 0);
                acc[m] = __builtin_amdgcn_mfma_f32_16x16x32_bf16(ah[c], wl[m][c], acc[m], 0, 0, 0);
            }
        }

#pragma unroll
        for (int r = 0; r < 4; r++) {
            const int row = rowbase + g * 4 + r;
            const size_t o = ((size_t)wave * NN + row) * 16 + n15;
            Kq[o]  = f2bf(acc[0][r] + bkc);
            QVq[o] = pack_bf16x2(__expf(-(acc[1][r] + bqc)), acc[2][r] + bvc);
            Hq[o]  = f2bf(acc[3][r] + bsc);
        }
    }
}

// ---------------------------------------------------------------------------
// CSR build: histogram of dst, two-level exclusive scan, scatter fill (u16).
// ---------------------------------------------------------------------------
__global__ __launch_bounds__(256) void deg_kernel(
    const int* __restrict__ ei, int* __restrict__ deg)
{
    const int e = blockIdx.x * 256 + threadIdx.x;
    if (e < NE) atomicAdd(&deg[ei[NE + e]], 1);
}

__global__ __launch_bounds__(256) void scan_partial_kernel(
    const int* __restrict__ deg, int* __restrict__ psums)
{
    __shared__ int ls[256];
    const int i = blockIdx.x * 256 + threadIdx.x;
    ls[threadIdx.x] = (i < NN) ? deg[i] : 0;
    __syncthreads();
    for (int off = 128; off > 0; off >>= 1) {
        if (threadIdx.x < off) ls[threadIdx.x] += ls[threadIdx.x + off];
        __syncthreads();
    }
    if (threadIdx.x == 0) psums[blockIdx.x] = ls[0];
}

__global__ void scan_offsets_kernel(int* __restrict__ psums, int* __restrict__ rowst)
{
    if (threadIdx.x == 0) {
        int running = 0;
        for (int i = 0; i < NCHUNK; i++) {
            int t = psums[i];
            psums[i] = running;
            running += t;
        }
        rowst[NN] = running;  // == NE
    }
}

__global__ __launch_bounds__(256) void scan_final_kernel(
    const int* __restrict__ deg, const int* __restrict__ psums,
    int* __restrict__ rowst, int* __restrict__ cursor)
{
    __shared__ int ls[256];
    const int i = blockIdx.x * 256 + threadIdx.x;
    const int x = (i < NN) ? deg[i] : 0;
    ls[threadIdx.x] = x;
    __syncthreads();
    for (int off = 1; off < 256; off <<= 1) {
        int v = (threadIdx.x >= off) ? ls[threadIdx.x - off] : 0;
        __syncthreads();
        ls[threadIdx.x] += v;
        __syncthreads();
    }
    if (i < NN) {
        const int excl = psums[blockIdx.x] + ls[threadIdx.x] - x;
        rowst[i]  = excl;
        cursor[i] = excl;
    }
}

__global__ __launch_bounds__(256) void fill_kernel(
    const int* __restrict__ ei, int* __restrict__ cursor,
    unsigned short* __restrict__ csr16)
{
    const int e = blockIdx.x * 256 + threadIdx.x;
    if (e < NE) {
        const int src = ei[e];         // < 50000 < 65536 -> u16 exact
        const int dst = ei[NE + e];
        csr16[atomicAdd(&cursor[dst], 1)] = (unsigned short)src;
    }
}

// ---------------------------------------------------------------------------
// Column-quarter XCD-partitioned gather, dual-node, SOFTWARE-PIPELINED
// index fetch: iteration t's Qq loads are issued from pre-fetched csr
// registers while iteration t+1's csr16 loads issue BEFORE the gates
// consume Qq -> csr and Qq latencies overlap (8 loads in flight/wave,
// no intra-iteration dependence). All loop conditions wave-uniform.
// Per node: ONE exp (e^-k); per edge: one rcp.
// ---------------------------------------------------------------------------
#define GATHER_BLOCKS (8 * 782)   // 6256
__global__ __launch_bounds__(256) void gather_kernel(
    const int* __restrict__ rowst, const unsigned short* __restrict__ csr16,
    const unsigned short* __restrict__ Kq, const unsigned int* __restrict__ QVq,
    unsigned short* Hq, float* __restrict__ stats)
{
    const int tid  = threadIdx.x;
    const int wv   = tid >> 6;
    const int lane = tid & 63;
    const int eoff = lane >> 4;     // edge slot 0..3
    const int cl   = lane & 15;     // column within quarter

    const int j       = blockIdx.x;
    const int xcd     = j & 7;
    const int quarter = xcd >> 1;
    const int half    = xcd & 1;
    const int nodebase = ((j >> 3) * 2 + half) * 32 + wv * 8;

    const unsigned short* Kqq = Kq + (size_t)quarter * NN * 16;
    const unsigned int*   Qq  = QVq + (size_t)quarter * NN * 16;
    unsigned short*       Hqq = Hq + (size_t)quarter * NN * 16;

    float s = 0.f, s2 = 0.f;

    for (int t = 0; t < 4; t++) {
        const int n0 = nodebase + 2 * t;     // even; n1 = n0+1 < NN when n0 < NN
        if (n0 >= NN) break;
        const int n1 = n0 + 1;
        const float ek0 = __expf(-bf2f(Kqq[(unsigned)(n0 * 16 + cl)]));
        const float ek1 = __expf(-bf2f(Kqq[(unsigned)(n1 * 16 + cl)]));
        const int e00 = rowst[n0], e01 = rowst[n1], e11 = rowst[n1 + 1];
        float a0 = 0.f, a1 = 0.f;
        int i0 = e00, i1 = e01;

        // ---- software-pipelined main loop (wave-uniform trip count) ----
        bool act = (i0 + 8 <= e01) && (i1 + 8 <= e11);
        int s00 = 0, s01 = 0, s10 = 0, s11 = 0;
        if (act) {
            s00 = csr16[i0 + eoff];
            s01 = csr16[i0 + 4 + eoff];
            s10 = csr16[i1 + eoff];
            s11 = csr16[i1 + 4 + eoff];
        }
        while (act) {
            // Qq loads from prefetched indices
            const unsigned p00 = Qq[(unsigned)(s00 * 16 + cl)];
            const unsigned p01 = Qq[(unsigned)(s01 * 16 + cl)];
            const unsigned p10 = Qq[(unsigned)(s10 * 16 + cl)];
            const unsigned p11 = Qq[(unsigned)(s11 * 16 + cl)];
            i0 += 8; i1 += 8;
            const bool actn = (i0 + 8 <= e01) && (i1 + 8 <= e11);
            int t00 = s00, t01 = s01, t10 = s10, t11 = s11;
            if (actn) {   // next iteration's csr loads — independent of p*
                t00 = csr16[i0 + eoff];
                t01 = csr16[i0 + 4 + eoff];
                t10 = csr16[i1 + eoff];
                t11 = csr16[i1 + 4 + eoff];
            }
            // consume Qq
            a0 = gate_fma(ek0, p00, a0);
            a0 = gate_fma(ek0, p01, a0);
            a1 = gate_fma(ek1, p10, a1);
            a1 = gate_fma(ek1, p11, a1);
            s00 = t00; s01 = t01; s10 = t10; s11 = t11;
            act = actn;
        }
        // node-0 cleanup
        for (; i0 + 4 <= e01; i0 += 4) {
            const int sx = csr16[i0 + eoff];
            a0 = gate_fma(ek0, Qq[(unsigned)(sx * 16 + cl)], a0);
        }
        if (i0 < e01) {
            const int idx = min(i0 + eoff, e01 - 1);
            const float gv = gate_fma(ek0, Qq[(unsigned)(csr16[idx] * 16 + cl)], 0.f);
            a0 += (i0 + eoff < e01) ? gv : 0.f;
        }
        // node-1 cleanup
        for (; i1 + 4 <= e11; i1 += 4) {
            const int sx = csr16[i1 + eoff];
            a1 = gate_fma(ek1, Qq[(unsigned)(sx * 16 + cl)], a1);
        }
        if (i1 < e11) {
            const int idx = min(i1 + eoff, e11 - 1);
            const float gv = gate_fma(ek1, Qq[(unsigned)(csr16[idx] * 16 + cl)], 0.f);
            a1 += (i1 + eoff < e11) ? gv : 0.f;
        }

        // combine edge slots (lanes l, l+16, l+32, l+48 share a column)
        a0 += __shfl_xor(a0, 16);
        a0 += __shfl_xor(a0, 32);
        a1 += __shfl_xor(a1, 16);
        a1 += __shfl_xor(a1, 32);
        if (eoff == 0) {
            const unsigned ho0 = (unsigned)(n0 * 16 + cl);
            const unsigned ho1 = (unsigned)(n1 * 16 + cl);
            const float o0 = fmaxf(bf2f(Hqq[ho0]) + a0, 0.f);
            const float o1 = fmaxf(bf2f(Hqq[ho1]) + a1, 0.f);
            const unsigned short ob0 = f2bf(o0);
            const unsigned short ob1 = f2bf(o1);
            Hqq[ho0] = ob0;
            Hqq[ho1] = ob1;
            const float r0 = bf2f(ob0), r1 = bf2f(ob1);
            s += r0 + r1;
            s2 += r0 * r0 + r1 * r1;
        }
    }

    __shared__ float ls[64], ls2[64];   // 4 waves x 16 cols
    if (eoff == 0) {
        ls[wv * 16 + cl]  = s;
        ls2[wv * 16 + cl] = s2;
    }
    __syncthreads();
    if (tid < 16) {
        const float a = ls[tid] + ls[16 + tid] + ls[32 + tid] + ls[48 + tid];
        const float b = ls2[tid] + ls2[16 + tid] + ls2[32 + tid] + ls2[48 + tid];
        atomicAdd(&stats[quarter * 16 + tid], a);
        atomicAdd(&stats[64 + quarter * 16 + tid], b);
    }
}

// ---------------------------------------------------------------------------
// Pooled segment-sum over quarter-major bf16 H (batch sorted).
// ---------------------------------------------------------------------------
#define POOL_ROWS 64
__global__ __launch_bounds__(64) void pool_kernel(
    const unsigned short* __restrict__ Hq, const int* __restrict__ batch,
    float* __restrict__ psum, float* __restrict__ pcnt)
{
    const int c  = threadIdx.x;
    const int q  = c >> 4;
    const int cl = c & 15;
    const int r0 = blockIdx.x * POOL_ROWS;
    if (r0 >= NN) return;
    const int r1 = min(r0 + POOL_ROWS, NN);
    const unsigned short* Hqq = Hq + (size_t)q * NN * 16;

    int cur = batch[r0];
    float acc = 0.f, cnt = 0.f;
    for (int r = r0; r < r1; r++) {
        const int g = batch[r];
        if (g != cur) {
            atomicAdd(&psum[cur * DD + c], acc);
            if (c == 0) atomicAdd(&pcnt[cur], cnt);
            acc = 0.f; cnt = 0.f; cur = g;
        }
        acc += bf2f(Hqq[(size_t)r * 16 + cl]);
        cnt += 1.f;
    }
    atomicAdd(&psum[cur * DD + c], acc);
    if (c == 0) atomicAdd(&pcnt[cur], cnt);
}

// ---------------------------------------------------------------------------
// Final: pooled mean -> folded last-layer BN affine -> logits -> softmax.
// ---------------------------------------------------------------------------
__global__ __launch_bounds__(256) void final_kernel(
    const float* __restrict__ psum, const float* __restrict__ pcnt,
    const float* __restrict__ stats,
    const float* __restrict__ gamma, const float* __restrict__ beta,
    const float* __restrict__ Wlin, const float* __restrict__ blin,
    float* __restrict__ out)
{
    const int g = blockIdx.x * blockDim.x + threadIdx.x;
    if (g >= NG) return;

    const float invc = 1.0f / fmaxf(pcnt[g], 1.0f);
    const float invN = 1.0f / (float)NN;
    float p[DD];
#pragma unroll
    for (int d = 0; d < DD; d++) {
        const float mean = stats[d] * invN;
        const float var  = stats[64 + d] * invN - mean * mean;
        const float inv  = rsqrtf(var + BN_EPS);
        const float a = inv * gamma[d];
        const float b = beta[d] - mean * a;
        p[d] = fmaf(psum[g * DD + d] * invc, a, b);
    }

    float logits[NC];
    float m = -1e30f;
#pragma unroll
    for (int c = 0; c < NC; c++) {
        float acc = blin[c];
#pragma unroll
        for (int d = 0; d < DD; d++) acc = fmaf(p[d], Wlin[d * NC + c], acc);
        logits[c] = acc;
        m = fmaxf(m, acc);
    }
    float sum = 0.f;
#pragma unroll
    for (int c = 0; c < NC; c++) {
        logits[c] = __expf(logits[c] - m);
        sum += logits[c];
    }
    const float inv = 1.f / sum;
#pragma unroll
    for (int c = 0; c < NC; c++) out[g * NC + c] = logits[c] * inv;
}

// ---------------------------------------------------------------------------
extern "C" void kernel_launch(void* const* d_in, const int* in_sizes, int n_in,
                              void* d_out, int out_size, void* d_ws, size_t ws_size,
                              hipStream_t stream)
{
    const float* X     = (const float*)d_in[0];
    const int*   ei    = (const int*)d_in[1];
    const int*   batch = (const int*)d_in[2];
    const float* Wk    = (const float*)d_in[3];
    const float* Wq    = (const float*)d_in[4];
    const float* Wv    = (const float*)d_in[5];
    const float* Ws    = (const float*)d_in[6];
    const float* bk    = (const float*)d_in[7];
    const float* bq    = (const float*)d_in[8];
    const float* bv    = (const float*)d_in[9];
    const float* bconv = (const float*)d_in[10];
    const float* gamma = (const float*)d_in[11];
    const float* beta  = (const float*)d_in[12];
    const float* Wlin  = (const float*)d_in[13];
    const float* blin  = (const float*)d_in[14];
    float* out = (float*)d_out;

    const size_t M = (size_t)NN * DD;   // == 4 * NN * 16
    unsigned short* Kq  = (unsigned short*)d_ws;      // M bf16, quarter-major
    unsigned int*   QVq = (unsigned int*)(Kq + M);    // M packed (e^-q|v)
    unsigned short* H0q = (unsigned short*)(QVq + M); // M bf16, quarter-major
    unsigned short* H1q = H0q + M;                    // M bf16
    // --- contiguous zero-init region ---
    int*   deg   = (int*)(H1q + M);                   // NN
    float* psum  = (float*)(deg + NN);                // NG*DD
    float* pcnt  = psum + (size_t)NG * DD;            // NG
    float* stats = pcnt + NG;                         // NL*128
    // --- end zero region ---
    int* rowst  = (int*)(stats + NL * 128);           // NN+1
    int* cursor = rowst + NN + 1;                     // NN
    int* psums  = cursor + NN;                        // 256
    unsigned short* csr16 = (unsigned short*)(psums + 256);  // NE u16
    bf16x8* whbuf = (bf16x8*)(csr16 + NE);            // NL*2048 frags
    bf16x8* wlbuf = whbuf + NL * 2048;

    const size_t zero_bytes = (size_t)(NN + NG * DD + NG + NL * 128) * sizeof(float);
    hipMemsetAsync(deg, 0, zero_bytes, stream);

    // ---- W fragment prep (all layers) ----
    wprep_kernel<<<(NL * 2048 + 255) / 256, 256, 0, stream>>>(
        Wk, Wq, Wv, Ws, whbuf, wlbuf);

    // ---- CSR build (u16 adjacency) ----
    deg_kernel<<<(NE + 255) / 256, 256, 0, stream>>>(ei, deg);
    scan_partial_kernel<<<NCHUNK, 256, 0, stream>>>(deg, psums);
    scan_offsets_kernel<<<1, 64, 0, stream>>>(psums, rowst);
    scan_final_kernel<<<NCHUNK, 256, 0, stream>>>(deg, psums, rowst, cursor);
    fill_kernel<<<(NE + 255) / 256, 256, 0, stream>>>(ei, cursor, csr16);

    // ---- layers (BN folded into next GEMM / final) ----
    const void* hin = (const void*)X;
    int hinF32 = 1;
    for (int l = 0; l < NL; l++) {
        unsigned short* hout = (l & 1) ? H1q : H0q;
        const float* pS = l ? stats + (l - 1) * 128 : nullptr;
        const float* pG = l ? gamma + (l - 1) * 64  : nullptr;
        const float* pB = l ? beta  + (l - 1) * 64  : nullptr;
        gemm4_mfma<<<GEMM_BLOCKS, 256, 0, stream>>>(
            hin, hinF32, whbuf + l * 2048, wlbuf + l * 2048,
            bk + l * 64, bq + l * 64, bv + l * 64, bconv + l * 64,
            pS, pG, pB, Kq, QVq, hout);
        gather_kernel<<<GATHER_BLOCKS, 256, 0, stream>>>(
            rowst, csr16, Kq, QVq, hout, stats + l * 128);
        hin = (const void*)hout;
        hinF32 = 0;
    }

    pool_kernel<<<(NN + POOL_ROWS - 1) / POOL_ROWS, 64, 0, stream>>>(
        (const unsigned short*)hin, batch, psum, pcnt);
    final_kernel<<<1, 256, 0, stream>>>(
        psum, pcnt, stats + 4 * 128, gamma + 4 * 64, beta + 4 * 64, Wlin, blin, out);
}

// Round 20
// 580.039 us; speedup vs baseline: 1.0961x; 1.0869x over previous
//
#include <hip/hip_runtime.h>

#define NN 50000
#define NE 800000
#define DD 64
#define NL 5
#define NG 256
#define NC 10
#define BN_EPS 1e-5f
#define NCHUNK ((NN + 255) / 256)   // 196
#define GROWS 128                    // rows per gemm block
#define GT (GROWS / 16)              // 16-row tiles per block
#define SAW 68                       // staged-A row stride (uints)
#define GEMM_BLOCKS ((NN + GROWS - 1) / GROWS)   // 391

typedef __attribute__((ext_vector_type(8))) short bf16x8;
typedef __attribute__((ext_vector_type(4))) float f32x4;

__device__ inline float bf2f(unsigned short u) {
    return __uint_as_float((unsigned)u << 16);
}
__device__ inline unsigned short f2bf(float x) {   // RNE
    unsigned u = __float_as_uint(x);
    u += 0x7FFFu + ((u >> 16) & 1u);
    return (unsigned short)(u >> 16);
}

// Pack two floats as bf16 (RNE) into one uint: low16 = a, high16 = b.
__device__ inline unsigned int pack_bf16x2(float a, float b) {
    unsigned int ua = __float_as_uint(a);
    unsigned int ub = __float_as_uint(b);
    ua += 0x7FFFu + ((ua >> 16) & 1u);
    ub += 0x7FFFu + ((ub >> 16) & 1u);
    return (ub & 0xFFFF0000u) | (ua >> 16);
}

// Split fp32 into bf16 hi (RTZ) + bf16 lo (residual). hi+lo ~ x to ~2^-17.
__device__ inline void split_bf16(float x, short& h, short& l) {
    const unsigned u  = __float_as_uint(x);
    const unsigned hb = u & 0xFFFF0000u;
    h = (short)(hb >> 16);
    const float lo = x - __uint_as_float(hb);
    l = (short)(__float_as_uint(lo) >> 16);
}

// gate value with PRE-EXPONENTIATED inputs: p packs (e^-q | v) bf16.
// sigmoid(k+q)*v = v / (1 + e^-k * e^-q). One rcp per gate.
__device__ inline float gate_val(float ek, unsigned p) {
    const float eq = __uint_as_float(p << 16);
    const float v  = __uint_as_float(p & 0xFFFF0000u);
    const float t  = fmaf(ek, eq, 1.f);
    return __builtin_amdgcn_rcpf(t) * v;
}

// ---------------------------------------------------------------------------
// W-fragment prep (all 5 layers upfront): split W into MFMA-read-order
// bf16 hi/lo fragment buffers. t = l*2048 + m*512 + c*256 + w*64 + lane.
// ---------------------------------------------------------------------------
__global__ __launch_bounds__(256) void wprep_kernel(
    const float* __restrict__ Wk, const float* __restrict__ Wq,
    const float* __restrict__ Wv, const float* __restrict__ Ws,
    bf16x8* __restrict__ whbuf, bf16x8* __restrict__ wlbuf)
{
    const int t = blockIdx.x * 256 + threadIdx.x;
    if (t >= NL * 2048) return;
    const int lane = t & 63;
    const int w    = (t >> 6) & 3;
    const int c    = (t >> 8) & 1;
    const int m    = (t >> 9) & 3;
    const int l    = t >> 11;

    const float* Wm4[4] = {Wk, Wq, Wv, Ws};
    const float* W = Wm4[m] + l * 4096;
    const int col = w * 16 + (lane & 15);
    const int g   = lane >> 4;

    bf16x8 h, lo;
#pragma unroll
    for (int j = 0; j < 8; j++) {
        const int k = g * 8 + j + 32 * c;
        short hs, ls;
        split_bf16(W[k * DD + col], hs, ls);
        h[j] = hs; lo[j] = ls;
    }
    whbuf[t] = h;
    wlbuf[t] = lo;
}

// ---------------------------------------------------------------------------
// MFMA gemm4 (inline prev-layer BN, QUARTER-MAJOR outputs):
//   Kq/QVq/Hq[quarter][node][16]. QVq packs (e^-q | v) — exp done here,
// once per (node,col), amortized over deg~16 edge-uses in gather.
// ---------------------------------------------------------------------------
__global__ __launch_bounds__(256) void gemm4_mfma(
    const void* __restrict__ HinV, const int hinF32,
    const bf16x8* __restrict__ whbuf, const bf16x8* __restrict__ wlbuf,
    const float* __restrict__ bk, const float* __restrict__ bq,
    const float* __restrict__ bv, const float* __restrict__ bs,
    const float* __restrict__ prevStats,   // null for layer 0
    const float* __restrict__ prevGamma, const float* __restrict__ prevBeta,
    unsigned short* __restrict__ Kq, unsigned int* __restrict__ QVq,
    unsigned short* __restrict__ Hq)
{
    __shared__ unsigned int sA[GROWS * SAW];   // packed split-bf16 A
    __shared__ float sAB[128];                 // a[64], b[64]
    const int tid = threadIdx.x;

    if (tid < 64) {
        float a = 1.f, b = 0.f;
        if (prevStats) {
            const float invN = 1.0f / (float)NN;
            const float mean = prevStats[tid] * invN;
            const float var  = prevStats[64 + tid] * invN - mean * mean;
            const float inv  = rsqrtf(var + BN_EPS);
            a = inv * prevGamma[tid];
            b = prevBeta[tid] - mean * a;
        }
        sAB[tid]      = a;
        sAB[64 + tid] = b;
    }
    __syncthreads();

    const int row0 = blockIdx.x * GROWS;
    if (hinF32) {
        const float* X = (const float*)HinV;
        for (int i = tid; i < GROWS * 16; i += 256) {
            const int row = i >> 4;
            const int k4  = (i & 15) * 4;
            float4 x = make_float4(0.f, 0.f, 0.f, 0.f);
            if (row0 + row < NN)
                x = *(const float4*)(X + (size_t)(row0 + row) * DD + k4);
            const float xs[4] = {x.x, x.y, x.z, x.w};
            unsigned int* dst = &sA[row * SAW + k4];
#pragma unroll
            for (int j = 0; j < 4; j++) {
                const float xv = fmaf(xs[j], sAB[k4 + j], sAB[64 + k4 + j]);
                short hs, ls;
                split_bf16(xv, hs, ls);
                dst[j] = ((unsigned int)(unsigned short)hs << 16) | (unsigned short)ls;
            }
        }
    } else {
        const unsigned short* Hin = (const unsigned short*)HinV;
        for (int i = tid; i < GROWS * 8; i += 256) {
            const int row = i >> 3;
            const int cb  = (i & 7) * 8;   // col base: 0,8,..,56
            const int q   = cb >> 4;
            const int o16 = cb & 15;       // 0 or 8
            uint4 v = make_uint4(0u, 0u, 0u, 0u);
            if (row0 + row < NN)
                v = *(const uint4*)&Hin[((size_t)q * NN + row0 + row) * 16 + o16];
            const unsigned ws[4] = {v.x, v.y, v.z, v.w};
            unsigned int* dst = &sA[row * SAW + cb];
#pragma unroll
            for (int j = 0; j < 4; j++) {
                const float x0 = bf2f((unsigned short)(ws[j] & 0xFFFFu));
                const float x1 = bf2f((unsigned short)(ws[j] >> 16));
                const int c0 = cb + 2 * j, c1 = cb + 2 * j + 1;
                short hs, ls;
                split_bf16(fmaf(x0, sAB[c0], sAB[64 + c0]), hs, ls);
                dst[2 * j] = ((unsigned int)(unsigned short)hs << 16) | (unsigned short)ls;
                split_bf16(fmaf(x1, sAB[c1], sAB[64 + c1]), hs, ls);
                dst[2 * j + 1] = ((unsigned int)(unsigned short)hs << 16) | (unsigned short)ls;
            }
        }
    }

    const int wave = tid >> 6;    // column tile == quarter
    const int lane = tid & 63;
    const int n15  = lane & 15;
    const int g    = lane >> 4;
    const int col  = wave * 16 + n15;

    bf16x8 wh[4][2], wl[4][2];
    {
        const int base = wave * 64 + lane;
#pragma unroll
        for (int m = 0; m < 4; m++)
#pragma unroll
            for (int c = 0; c < 2; c++) {
                const int idx = m * 512 + c * 256 + base;
                wh[m][c] = whbuf[idx];
                wl[m][c] = wlbuf[idx];
            }
    }

    const float bkc = bk[col], bqc = bq[col], bvc = bv[col], bsc = bs[col];
    __syncthreads();

#pragma unroll 1
    for (int t = 0; t < GT; t++) {
        const int rowbase = row0 + t * 16;
        if (rowbase >= NN) break;   // NN % 16 == 0

        bf16x8 ah[2], al[2];
#pragma unroll
        for (int c = 0; c < 2; c++) {
            const uint4 u0 = *(const uint4*)&sA[(t * 16 + n15) * SAW + g * 8 + 32 * c];
            const uint4 u1 = *(const uint4*)&sA[(t * 16 + n15) * SAW + g * 8 + 32 * c + 4];
            const unsigned int us[8] = {u0.x, u0.y, u0.z, u0.w, u1.x, u1.y, u1.z, u1.w};
            bf16x8 h, l;
#pragma unroll
            for (int j = 0; j < 8; j++) {
                h[j] = (short)(us[j] >> 16);
                l[j] = (short)(us[j] & 0xFFFFu);
            }
            ah[c] = h; al[c] = l;
        }

        f32x4 acc[4];
#pragma unroll
        for (int m = 0; m < 4; m++) acc[m] = (f32x4){0.f, 0.f, 0.f, 0.f};

#pragma unroll
        for (int c = 0; c < 2; c++) {
#pragma unroll
            for (int m = 0; m < 4; m++) {
                acc[m] = __builtin_amdgcn_mfma_f32_16x16x32_bf16(ah[c], wh[m][c], acc[m], 0, 0, 0);
                acc[m] = __builtin_amdgcn_mfma_f32_16x16x32_bf16(al[c], wh[m][c], acc[m], 0, 0, 0);
                acc[m] = __builtin_amdgcn_mfma_f32_16x16x32_bf16(ah[c], wl[m][c], acc[m], 0, 0, 0);
            }
        }

#pragma unroll
        for (int r = 0; r < 4; r++) {
            const int row = rowbase + g * 4 + r;
            const size_t o = ((size_t)wave * NN + row) * 16 + n15;
            Kq[o]  = f2bf(acc[0][r] + bkc);
            QVq[o] = pack_bf16x2(__expf(-(acc[1][r] + bqc)), acc[2][r] + bvc);
            Hq[o]  = f2bf(acc[3][r] + bsc);
        }
    }
}

// ---------------------------------------------------------------------------
// CSR build: histogram of dst, two-level exclusive scan, scatter fill (u16).
// ---------------------------------------------------------------------------
__global__ __launch_bounds__(256) void deg_kernel(
    const int* __restrict__ ei, int* __restrict__ deg)
{
    const int e = blockIdx.x * 256 + threadIdx.x;
    if (e < NE) atomicAdd(&deg[ei[NE + e]], 1);
}

__global__ __launch_bounds__(256) void scan_partial_kernel(
    const int* __restrict__ deg, int* __restrict__ psums)
{
    __shared__ int ls[256];
    const int i = blockIdx.x * 256 + threadIdx.x;
    ls[threadIdx.x] = (i < NN) ? deg[i] : 0;
    __syncthreads();
    for (int off = 128; off > 0; off >>= 1) {
        if (threadIdx.x < off) ls[threadIdx.x] += ls[threadIdx.x + off];
        __syncthreads();
    }
    if (threadIdx.x == 0) psums[blockIdx.x] = ls[0];
}

__global__ void scan_offsets_kernel(int* __restrict__ psums, int* __restrict__ rowst)
{
    if (threadIdx.x == 0) {
        int running = 0;
        for (int i = 0; i < NCHUNK; i++) {
            int t = psums[i];
            psums[i] = running;
            running += t;
        }
        rowst[NN] = running;  // == NE
    }
}

__global__ __launch_bounds__(256) void scan_final_kernel(
    const int* __restrict__ deg, const int* __restrict__ psums,
    int* __restrict__ rowst, int* __restrict__ cursor)
{
    __shared__ int ls[256];
    const int i = blockIdx.x * 256 + threadIdx.x;
    const int x = (i < NN) ? deg[i] : 0;
    ls[threadIdx.x] = x;
    __syncthreads();
    for (int off = 1; off < 256; off <<= 1) {
        int v = (threadIdx.x >= off) ? ls[threadIdx.x - off] : 0;
        __syncthreads();
        ls[threadIdx.x] += v;
        __syncthreads();
    }
    if (i < NN) {
        const int excl = psums[blockIdx.x] + ls[threadIdx.x] - x;
        rowst[i]  = excl;
        cursor[i] = excl;
    }
}

__global__ __launch_bounds__(256) void fill_kernel(
    const int* __restrict__ ei, int* __restrict__ cursor,
    unsigned short* __restrict__ csr16)
{
    const int e = blockIdx.x * 256 + threadIdx.x;
    if (e < NE) {
        const int src = ei[e];         // < 50000 < 65536 -> u16 exact
        const int dst = ei[NE + e];
        csr16[atomicAdd(&cursor[dst], 1)] = (unsigned short)src;
    }
}

// ---------------------------------------------------------------------------
// Column-quarter XCD-partitioned gather, WIDE LOADS: lane = edge-slot(0-7)*8
// + col-pair(0-7); each lane loads uint2 (2 cols) -> ONE wave instruction
// covers 8 edges x 16 cols = HALF the vector-memory instructions of R19
// (tests the TA/issue-bound hypothesis). Masked 8-edge iterations (clamped
// index, predicated add), dual-node for ILP, shfl_xor(8,16,32) combine.
// Per node: one exp per col; per edge-col: one rcp. K/H moved as u32.
// ---------------------------------------------------------------------------
#define GATHER_BLOCKS (8 * 782)   // 6256
__global__ __launch_bounds__(256) void gather_kernel(
    const int* __restrict__ rowst, const unsigned short* __restrict__ csr16,
    const unsigned short* __restrict__ Kq, const unsigned int* __restrict__ QVq,
    unsigned short* Hq, float* __restrict__ stats)
{
    const int tid  = threadIdx.x;
    const int wv   = tid >> 6;
    const int lane = tid & 63;
    const int eoff = lane >> 3;     // edge slot 0..7
    const int cp   = lane & 7;      // column pair (cols 2cp, 2cp+1)

    const int j       = blockIdx.x;
    const int xcd     = j & 7;
    const int quarter = xcd >> 1;
    const int half    = xcd & 1;
    const int nodebase = ((j >> 3) * 2 + half) * 32 + wv * 8;

    const unsigned* Kq32 = (const unsigned*)(Kq + (size_t)quarter * NN * 16);
    const uint2*    Qq2  = (const uint2*)(QVq + (size_t)quarter * NN * 16);
    unsigned*       Hq32 = (unsigned*)(Hq + (size_t)quarter * NN * 16);

    float se = 0.f, s2e = 0.f, so = 0.f, s2o = 0.f;   // stats cols 2cp / 2cp+1

    for (int t = 0; t < 4; t++) {
        const int n0 = nodebase + 2 * t;   // even; n1 = n0+1 < NN when n0 < NN
        if (n0 >= NN) break;
        const int n1 = n0 + 1;
        const unsigned k0p = Kq32[(unsigned)(n0 * 8 + cp)];
        const unsigned k1p = Kq32[(unsigned)(n1 * 8 + cp)];
        const float ek00 = __expf(-bf2f((unsigned short)(k0p & 0xFFFFu)));
        const float ek01 = __expf(-bf2f((unsigned short)(k0p >> 16)));
        const float ek10 = __expf(-bf2f((unsigned short)(k1p & 0xFFFFu)));
        const float ek11 = __expf(-bf2f((unsigned short)(k1p >> 16)));
        const int e00 = rowst[n0], e01 = rowst[n1], e11 = rowst[n1 + 1];
        float a00 = 0.f, a01 = 0.f, a10 = 0.f, a11 = 0.f;
        int i0 = e00, i1 = e01;

        // dual-node masked main loop: 2 csr + 2 uint2 Qq loads in flight,
        // 8 edges x 16 cols per instruction
        while (i0 < e01 && i1 < e11) {
            const int x0 = min(i0 + eoff, e01 - 1);
            const int x1 = min(i1 + eoff, e11 - 1);
            const int s0 = csr16[x0];
            const int s1 = csr16[x1];
            const uint2 p0 = Qq2[(unsigned)(s0 * 8 + cp)];
            const uint2 p1 = Qq2[(unsigned)(s1 * 8 + cp)];
            const bool m0 = (i0 + eoff < e01);
            const bool m1 = (i1 + eoff < e11);
            const float g00 = gate_val(ek00, p0.x);
            const float g01 = gate_val(ek01, p0.y);
            const float g10 = gate_val(ek10, p1.x);
            const float g11 = gate_val(ek11, p1.y);
            a00 += m0 ? g00 : 0.f;
            a01 += m0 ? g01 : 0.f;
            a10 += m1 ? g10 : 0.f;
            a11 += m1 ? g11 : 0.f;
            i0 += 8; i1 += 8;
        }
        while (i0 < e01) {   // node-0 leftover
            const int x0 = min(i0 + eoff, e01 - 1);
            const int s0 = csr16[x0];
            const uint2 p0 = Qq2[(unsigned)(s0 * 8 + cp)];
            const bool m0 = (i0 + eoff < e01);
            const float g00 = gate_val(ek00, p0.x);
            const float g01 = gate_val(ek01, p0.y);
            a00 += m0 ? g00 : 0.f;
            a01 += m0 ? g01 : 0.f;
            i0 += 8;
        }
        while (i1 < e11) {   // node-1 leftover
            const int x1 = min(i1 + eoff, e11 - 1);
            const int s1 = csr16[x1];
            const uint2 p1 = Qq2[(unsigned)(s1 * 8 + cp)];
            const bool m1 = (i1 + eoff < e11);
            const float g10 = gate_val(ek10, p1.x);
            const float g11 = gate_val(ek11, p1.y);
            a10 += m1 ? g10 : 0.f;
            a11 += m1 ? g11 : 0.f;
            i1 += 8;
        }

        // combine edge slots: lanes cp, cp+8, ..., cp+56 share columns
        a00 += __shfl_xor(a00, 8);  a00 += __shfl_xor(a00, 16); a00 += __shfl_xor(a00, 32);
        a01 += __shfl_xor(a01, 8);  a01 += __shfl_xor(a01, 16); a01 += __shfl_xor(a01, 32);
        a10 += __shfl_xor(a10, 8);  a10 += __shfl_xor(a10, 16); a10 += __shfl_xor(a10, 32);
        a11 += __shfl_xor(a11, 8);  a11 += __shfl_xor(a11, 16); a11 += __shfl_xor(a11, 32);

        if (eoff == 0) {
            const unsigned ho0 = (unsigned)(n0 * 8 + cp);
            const unsigned ho1 = (unsigned)(n1 * 8 + cp);
            const unsigned h0p = Hq32[ho0];
            const unsigned h1p = Hq32[ho1];
            const float o00 = fmaxf(bf2f((unsigned short)(h0p & 0xFFFFu)) + a00, 0.f);
            const float o01 = fmaxf(bf2f((unsigned short)(h0p >> 16))     + a01, 0.f);
            const float o10 = fmaxf(bf2f((unsigned short)(h1p & 0xFFFFu)) + a10, 0.f);
            const float o11 = fmaxf(bf2f((unsigned short)(h1p >> 16))     + a11, 0.f);
            const unsigned short b00 = f2bf(o00), b01 = f2bf(o01);
            const unsigned short b10 = f2bf(o10), b11 = f2bf(o11);
            Hq32[ho0] = ((unsigned)b01 << 16) | b00;
            Hq32[ho1] = ((unsigned)b11 << 16) | b10;
            const float r00 = bf2f(b00), r01 = bf2f(b01);
            const float r10 = bf2f(b10), r11 = bf2f(b11);
            se  += r00 + r10;  s2e += r00 * r00 + r10 * r10;
            so  += r01 + r11;  s2o += r01 * r01 + r11 * r11;
        }
    }

    __shared__ float ls[64], ls2[64];   // 4 waves x 16 cols
    if (eoff == 0) {
        ls[wv * 16 + 2 * cp]      = se;  ls2[wv * 16 + 2 * cp]      = s2e;
        ls[wv * 16 + 2 * cp + 1]  = so;  ls2[wv * 16 + 2 * cp + 1]  = s2o;
    }
    __syncthreads();
    if (tid < 16) {
        const float a = ls[tid] + ls[16 + tid] + ls[32 + tid] + ls[48 + tid];
        const float b = ls2[tid] + ls2[16 + tid] + ls2[32 + tid] + ls2[48 + tid];
        atomicAdd(&stats[quarter * 16 + tid], a);
        atomicAdd(&stats[64 + quarter * 16 + tid], b);
    }
}

// ---------------------------------------------------------------------------
// Pooled segment-sum over quarter-major bf16 H (batch sorted).
// ---------------------------------------------------------------------------
#define POOL_ROWS 64
__global__ __launch_bounds__(64) void pool_kernel(
    const unsigned short* __restrict__ Hq, const int* __restrict__ batch,
    float* __restrict__ psum, float* __restrict__ pcnt)
{
    const int c  = threadIdx.x;
    const int q  = c >> 4;
    const int cl = c & 15;
    const int r0 = blockIdx.x * POOL_ROWS;
    if (r0 >= NN) return;
    const int r1 = min(r0 + POOL_ROWS, NN);
    const unsigned short* Hqq = Hq + (size_t)q * NN * 16;

    int cur = batch[r0];
    float acc = 0.f, cnt = 0.f;
    for (int r = r0; r < r1; r++) {
        const int g = batch[r];
        if (g != cur) {
            atomicAdd(&psum[cur * DD + c], acc);
            if (c == 0) atomicAdd(&pcnt[cur], cnt);
            acc = 0.f; cnt = 0.f; cur = g;
        }
        acc += bf2f(Hqq[(size_t)r * 16 + cl]);
        cnt += 1.f;
    }
    atomicAdd(&psum[cur * DD + c], acc);
    if (c == 0) atomicAdd(&pcnt[cur], cnt);
}

// ---------------------------------------------------------------------------
// Final: pooled mean -> folded last-layer BN affine -> logits -> softmax.
// ---------------------------------------------------------------------------
__global__ __launch_bounds__(256) void final_kernel(
    const float* __restrict__ psum, const float* __restrict__ pcnt,
    const float* __restrict__ stats,
    const float* __restrict__ gamma, const float* __restrict__ beta,
    const float* __restrict__ Wlin, const float* __restrict__ blin,
    float* __restrict__ out)
{
    const int g = blockIdx.x * blockDim.x + threadIdx.x;
    if (g >= NG) return;

    const float invc = 1.0f / fmaxf(pcnt[g], 1.0f);
    const float invN = 1.0f / (float)NN;
    float p[DD];
#pragma unroll
    for (int d = 0; d < DD; d++) {
        const float mean = stats[d] * invN;
        const float var  = stats[64 + d] * invN - mean * mean;
        const float inv  = rsqrtf(var + BN_EPS);
        const float a = inv * gamma[d];
        const float b = beta[d] - mean * a;
        p[d] = fmaf(psum[g * DD + d] * invc, a, b);
    }

    float logits[NC];
    float m = -1e30f;
#pragma unroll
    for (int c = 0; c < NC; c++) {
        float acc = blin[c];
#pragma unroll
        for (int d = 0; d < DD; d++) acc = fmaf(p[d], Wlin[d * NC + c], acc);
        logits[c] = acc;
        m = fmaxf(m, acc);
    }
    float sum = 0.f;
#pragma unroll
    for (int c = 0; c < NC; c++) {
        logits[c] = __expf(logits[c] - m);
        sum += logits[c];
    }
    const float inv = 1.f / sum;
#pragma unroll
    for (int c = 0; c < NC; c++) out[g * NC + c] = logits[c] * inv;
}

// ---------------------------------------------------------------------------
extern "C" void kernel_launch(void* const* d_in, const int* in_sizes, int n_in,
                              void* d_out, int out_size, void* d_ws, size_t ws_size,
                              hipStream_t stream)
{
    const float* X     = (const float*)d_in[0];
    const int*   ei    = (const int*)d_in[1];
    const int*   batch = (const int*)d_in[2];
    const float* Wk    = (const float*)d_in[3];
    const float* Wq    = (const float*)d_in[4];
    const float* Wv    = (const float*)d_in[5];
    const float* Ws    = (const float*)d_in[6];
    const float* bk    = (const float*)d_in[7];
    const float* bq    = (const float*)d_in[8];
    const float* bv    = (const float*)d_in[9];
    const float* bconv = (const float*)d_in[10];
    const float* gamma = (const float*)d_in[11];
    const float* beta  = (const float*)d_in[12];
    const float* Wlin  = (const float*)d_in[13];
    const float* blin  = (const float*)d_in[14];
    float* out = (float*)d_out;

    const size_t M = (size_t)NN * DD;   // == 4 * NN * 16
    unsigned short* Kq  = (unsigned short*)d_ws;      // M bf16, quarter-major
    unsigned int*   QVq = (unsigned int*)(Kq + M);    // M packed (e^-q|v)
    unsigned short* H0q = (unsigned short*)(QVq + M); // M bf16, quarter-major
    unsigned short* H1q = H0q + M;                    // M bf16
    // --- contiguous zero-init region ---
    int*   deg   = (int*)(H1q + M);                   // NN
    float* psum  = (float*)(deg + NN);                // NG*DD
    float* pcnt  = psum + (size_t)NG * DD;            // NG
    float* stats = pcnt + NG;                         // NL*128
    // --- end zero region ---
    int* rowst  = (int*)(stats + NL * 128);           // NN+1
    int* cursor = rowst + NN + 1;                     // NN
    int* psums  = cursor + NN;                        // 256
    unsigned short* csr16 = (unsigned short*)(psums + 256);  // NE u16
    bf16x8* whbuf = (bf16x8*)(csr16 + NE);            // NL*2048 frags
    bf16x8* wlbuf = whbuf + NL * 2048;

    const size_t zero_bytes = (size_t)(NN + NG * DD + NG + NL * 128) * sizeof(float);
    hipMemsetAsync(deg, 0, zero_bytes, stream);

    // ---- W fragment prep (all layers) ----
    wprep_kernel<<<(NL * 2048 + 255) / 256, 256, 0, stream>>>(
        Wk, Wq, Wv, Ws, whbuf, wlbuf);

    // ---- CSR build (u16 adjacency) ----
    deg_kernel<<<(NE + 255) / 256, 256, 0, stream>>>(ei, deg);
    scan_partial_kernel<<<NCHUNK, 256, 0, stream>>>(deg, psums);
    scan_offsets_kernel<<<1, 64, 0, stream>>>(psums, rowst);
    scan_final_kernel<<<NCHUNK, 256, 0, stream>>>(deg, psums, rowst, cursor);
    fill_kernel<<<(NE + 255) / 256, 256, 0, stream>>>(ei, cursor, csr16);

    // ---- layers (BN folded into next GEMM / final) ----
    const void* hin = (const void*)X;
    int hinF32 = 1;
    for (int l = 0; l < NL; l++) {
        unsigned short* hout = (l & 1) ? H1q : H0q;
        const float* pS = l ? stats + (l - 1) * 128 : nullptr;
        const float* pG = l ? gamma + (l - 1) * 64  : nullptr;
        const float* pB = l ? beta  + (l - 1) * 64  : nullptr;
        gemm4_mfma<<<GEMM_BLOCKS, 256, 0, stream>>>(
            hin, hinF32, whbuf + l * 2048, wlbuf + l * 2048,
            bk + l * 64, bq + l * 64, bv + l * 64, bconv + l * 64,
            pS, pG, pB, Kq, QVq, hout);
        gather_kernel<<<GATHER_BLOCKS, 256, 0, stream>>>(
            rowst, csr16, Kq, QVq, hout, stats + l * 128);
        hin = (const void*)hout;
        hinF32 = 0;
    }

    pool_kernel<<<(NN + POOL_ROWS - 1) / POOL_ROWS, 64, 0, stream>>>(
        (const unsigned short*)hin, batch, psum, pcnt);
    final_kernel<<<1, 256, 0, stream>>>(
        psum, pcnt, stats + 4 * 128, gamma + 4 * 64, beta + 4 * 64, Wlin, blin, out);
}